// Round 2
// baseline (339.686 us; speedup 1.0000x reference)
//
#include <hip/hip_runtime.h>
#include <math.h>

#define Bq 4
#define Lq 2048
#define NH 8
#define LDP2 40   // attn Pp row stride (ushorts)

typedef __attribute__((ext_vector_type(8))) __bf16 bf16x8;
typedef __attribute__((ext_vector_type(4))) float f32x4;
#define MFMA16(a,b,c) __builtin_amdgcn_mfma_f32_16x16x32_bf16(a,b,c,0,0,0)

__device__ __forceinline__ void async16(const void* g, void* l) {
    __builtin_amdgcn_global_load_lds(
        (const __attribute__((address_space(1))) unsigned int*)g,
        (__attribute__((address_space(3))) unsigned int*)l, 16, 0, 0);
}

// truncation split: x = hi + lo (+ ~2^-16 rel residual)
__device__ __forceinline__ void splitbf(float x, ushort& h, ushort& l) {
    unsigned u = __float_as_uint(x);
    h = (ushort)(u >> 16);
    float hf = __uint_as_float(u & 0xffff0000u);
    l = (ushort)(__float_as_uint(x - hf) >> 16);
}
// round-to-nearest-even bf16
__device__ __forceinline__ ushort rnebf(float x) {
    unsigned u = __float_as_uint(x);
    return (ushort)((u + 0x7fffu + ((u >> 16) & 1u)) >> 16);
}

// ---- W [512k][512n] fp32 -> WT [z*512 + n][k] bf16 hi/lo planes ----
__global__ __launch_bounds__(256) void wsplit3_kernel(
    const float* __restrict__ W0, const float* __restrict__ W1, const float* __restrict__ W2,
    ushort* __restrict__ WTh, ushort* __restrict__ WTl)
{
    __shared__ float T[64][65];
    const int z = blockIdx.z;
    const float* W = (z == 0) ? W0 : (z == 1) ? W1 : W2;
    const int k0 = blockIdx.x * 64, n0 = blockIdx.y * 64;
    const int tid = threadIdx.x;
    #pragma unroll
    for (int i = 0; i < 4; ++i) {
        int u = tid + i * 256;
        int row = u >> 4, c4 = (u & 15) * 4;
        float4 v = *(const float4*)(W + (size_t)(k0 + row) * 512 + n0 + c4);
        T[row][c4 + 0] = v.x; T[row][c4 + 1] = v.y; T[row][c4 + 2] = v.z; T[row][c4 + 3] = v.w;
    }
    __syncthreads();
    #pragma unroll
    for (int i = 0; i < 2; ++i) {
        int u = tid + i * 256;
        int d = u >> 3, c8 = (u & 7) * 8;
        ushort hs[8], ls[8];
        #pragma unroll
        for (int j = 0; j < 8; ++j) splitbf(T[c8 + j][d], hs[j], ls[j]);
        uint4 wh, wl;
        wh.x = hs[0] | ((unsigned)hs[1] << 16); wh.y = hs[2] | ((unsigned)hs[3] << 16);
        wh.z = hs[4] | ((unsigned)hs[5] << 16); wh.w = hs[6] | ((unsigned)hs[7] << 16);
        wl.x = ls[0] | ((unsigned)ls[1] << 16); wl.y = ls[2] | ((unsigned)ls[3] << 16);
        wl.z = ls[4] | ((unsigned)ls[5] << 16); wl.w = ls[6] | ((unsigned)ls[7] << 16);
        size_t off = (size_t)(z * 512 + n0 + d) * 512 + k0 + c8;
        *(uint4*)(WTh + off) = wh;
        *(uint4*)(WTl + off) = wl;
    }
}

// ---- GEMM2: 128x64 tile, BK=32, 4 waves (64x32 each), dbuf async-B staging ----
// final_=0: mi = y>>3 selects 0->Q split planes, 1->K hi plane, 2->V^T split planes
// final_=1: fp32 out to Cf
union GS {
    struct {
        ushort Ah[2][128 * 40];
        ushort Al[2][128 * 40];
        ushort Bh[2][2048];
        ushort Bl[2][2048];
    } s;
    ushort E[57344 / 2];
};

__global__ __launch_bounds__(256) void gemm2_kernel(
    const float* __restrict__ A0, const float* __restrict__ A1, const float* __restrict__ A2,
    const ushort* __restrict__ BhT, const ushort* __restrict__ BlT,
    const float* __restrict__ b0, const float* __restrict__ b1, const float* __restrict__ b2,
    int final_, float* __restrict__ Cf,
    ushort* __restrict__ Qh, ushort* __restrict__ Ql, ushort* __restrict__ Khp,
    ushort* __restrict__ VhT, ushort* __restrict__ VlT)
{
    __shared__ __align__(16) GS gs;
    const int tid = threadIdx.x;
    const int wave = tid >> 6, lane = tid & 63;
    const int l15 = lane & 15, quad = lane >> 4;
    const int m0 = blockIdx.x * 128;
    const int yy = blockIdx.y;
    const int mi = yy >> 3, n0 = (yy & 7) * 64;
    const int nglob = mi * 512 + n0;
    const float* A = (mi == 0) ? A0 : (mi == 1) ? A1 : A2;
    const float* bias = (mi == 0) ? b0 : (mi == 1) ? b1 : b2;
    const int wm = (wave & 1) * 64, wn = (wave >> 1) * 32;

    // A staging (register path, needs splitbf): rows am+32i, chunk ak4
    const int am = tid >> 3, ak4 = (tid & 7) * 4;
    // B staging (async): wave stages rows wave*16..+15 of both planes, XOR-swizzled
    const int brow = lane >> 2, bsrc = (lane & 3) ^ (brow & 3);
    const ushort* bhp = BhT + (size_t)(nglob + wave * 16 + brow) * 512 + bsrc * 8;
    const ushort* blp = BlT + (size_t)(nglob + wave * 16 + brow) * 512 + bsrc * 8;
    const int bdst = wave * 512 + lane * 8;   // ushort idx; byte = uniform + lane*16

    f32x4 acc[4][2];
    #pragma unroll
    for (int i = 0; i < 4; ++i)
        #pragma unroll
        for (int j = 0; j < 2; ++j) acc[i][j] = (f32x4){0.f, 0.f, 0.f, 0.f};

    float4 av[4];
    #pragma unroll
    for (int i = 0; i < 4; ++i)
        av[i] = *(const float4*)(A + (size_t)(m0 + am + 32 * i) * 512 + ak4);
    async16(bhp, &gs.s.Bh[0][bdst]);
    async16(blp, &gs.s.Bl[0][bdst]);
    #pragma unroll
    for (int i = 0; i < 4; ++i) {
        ushort4 h4, l4;
        splitbf(av[i].x, h4.x, l4.x); splitbf(av[i].y, h4.y, l4.y);
        splitbf(av[i].z, h4.z, l4.z); splitbf(av[i].w, h4.w, l4.w);
        *(ushort4*)&gs.s.Ah[0][(am + 32 * i) * 40 + ak4] = h4;
        *(ushort4*)&gs.s.Al[0][(am + 32 * i) * 40 + ak4] = l4;
    }

    for (int t = 0; t < 16; ++t) {
        const int p = t & 1;
        __syncthreads();   // drains async B(t) + A writes(t); all reads of buf 1-p done
        if (t < 15) {
            const int kn = (t + 1) * 32;
            async16(bhp + kn, &gs.s.Bh[1 - p][bdst]);
            async16(blp + kn, &gs.s.Bl[1 - p][bdst]);
            #pragma unroll
            for (int i = 0; i < 4; ++i)
                av[i] = *(const float4*)(A + (size_t)(m0 + am + 32 * i) * 512 + kn + ak4);
        }
        bf16x8 afh[4], afl[4];
        #pragma unroll
        for (int ms = 0; ms < 4; ++ms) {
            int off = (wm + ms * 16 + l15) * 40 + quad * 8;
            afh[ms] = *(const bf16x8*)&gs.s.Ah[p][off];
            afl[ms] = *(const bf16x8*)&gs.s.Al[p][off];
        }
        #pragma unroll
        for (int ns = 0; ns < 2; ++ns) {
            int off = (wn + ns * 16 + l15) * 32 + (quad ^ (l15 & 3)) * 8;
            bf16x8 bfh = *(const bf16x8*)&gs.s.Bh[p][off];
            bf16x8 bfl = *(const bf16x8*)&gs.s.Bl[p][off];
            #pragma unroll
            for (int ms = 0; ms < 4; ++ms) {
                acc[ms][ns] = MFMA16(afh[ms], bfl, acc[ms][ns]);
                acc[ms][ns] = MFMA16(afl[ms], bfh, acc[ms][ns]);
                acc[ms][ns] = MFMA16(afh[ms], bfh, acc[ms][ns]);
            }
        }
        if (t < 15) {
            #pragma unroll
            for (int i = 0; i < 4; ++i) {
                ushort4 h4, l4;
                splitbf(av[i].x, h4.x, l4.x); splitbf(av[i].y, h4.y, l4.y);
                splitbf(av[i].z, h4.z, l4.z); splitbf(av[i].w, h4.w, l4.w);
                *(ushort4*)&gs.s.Ah[1 - p][(am + 32 * i) * 40 + ak4] = h4;
                *(ushort4*)&gs.s.Al[1 - p][(am + 32 * i) * 40 + ak4] = l4;
            }
        }
    }

    // bias
    #pragma unroll
    for (int ns = 0; ns < 2; ++ns) {
        float bv = bias[n0 + wn + ns * 16 + l15];
        #pragma unroll
        for (int ms = 0; ms < 4; ++ms)
            #pragma unroll
            for (int r = 0; r < 4; ++r) acc[ms][ns][r] += bv;
    }

    if (final_) {   // coalesced fp32 stores (16 lanes x 4B = 64B lines)
        #pragma unroll
        for (int ns = 0; ns < 2; ++ns) {
            int col = n0 + wn + ns * 16 + l15;
            #pragma unroll
            for (int ms = 0; ms < 4; ++ms)
                #pragma unroll
                for (int r = 0; r < 4; ++r)
                    Cf[(size_t)(m0 + wm + ms * 16 + quad * 4 + r) * 512 + col] = acc[ms][ns][r];
        }
        return;
    }

    const int h0 = n0 >> 6;
    const int b = m0 >> 11, rr0 = m0 & 2047;
    const int passes = (mi == 1) ? 1 : 2;
    for (int pass = 0; pass < passes; ++pass) {
        __syncthreads();
        // acc -> LDS (V: transposed [col][row], b64; Q/K: row-major [row][col], b16)
        #pragma unroll
        for (int ms = 0; ms < 4; ++ms) {
            #pragma unroll
            for (int ns = 0; ns < 2; ++ns) {
                int cl = wn + ns * 16 + l15;
                int rl = wm + ms * 16 + quad * 4;
                if (mi == 2) {
                    ushort4 w4;
                    #pragma unroll
                    for (int r = 0; r < 4; ++r) {
                        ushort h, l; splitbf(acc[ms][ns][r], h, l);
                        ((ushort*)&w4)[r] = pass ? l : h;
                    }
                    *(ushort4*)&gs.E[cl * 136 + rl] = w4;
                } else {
                    #pragma unroll
                    for (int r = 0; r < 4; ++r) {
                        float v = acc[ms][ns][r];
                        ushort out;
                        if (mi == 1) out = rnebf(v);
                        else { ushort h, l; splitbf(v, h, l); out = pass ? l : h; }
                        gs.E[(rl + r) * 72 + cl] = out;
                    }
                }
            }
        }
        __syncthreads();
        // LDS -> global, wide coalesced uint4
        if (mi == 2) {
            ushort* dst = pass ? VlT : VhT;
            #pragma unroll
            for (int i = 0; i < 4; ++i) {
                int idx = tid + i * 256;
                int d = idx >> 4, rg = idx & 15;
                uint4 u = *(const uint4*)&gs.E[d * 136 + rg * 8];
                *(uint4*)&dst[((size_t)(b * 8 + h0) * 64 + d) * 2048 + rr0 + rg * 8] = u;
            }
        } else {
            ushort* dst = (mi == 0) ? (pass ? Ql : Qh) : Khp;
            #pragma unroll
            for (int i = 0; i < 4; ++i) {
                int idx = tid + i * 256;
                int row = idx >> 3, cg = idx & 7;
                uint4 u = *(const uint4*)&gs.E[row * 72 + cg * 8];
                *(uint4*)&dst[((size_t)(b * 8 + h0) * 2048 + rr0 + row) * 64 + cg * 8] = u;
            }
        }
    }
}

// ---- Flash attention, S^T dataflow, in-block split-K, 512 threads ----
// v2: no K/V LDS staging, no main-loop barriers. K/V MFMA fragments are
// per-lane-contiguous in global (K row-major in d, V^T row-major in kv), and
// K/V per (b,h) is L2-resident (768 KB; all 8 q-blocks of a bh land on one
// XCD since grid id = x + 32y, 32 % 8 == 0). K prefetched one t ahead
// (hidden under PV); the 4 waves of a half issue identical K/V addresses ->
// L1 broadcast. LDS keeps only per-wave Pp (+ epilogue Obuf union): 69 KB.
union SmemU {
    struct { ushort Pp[8][64 * LDP2]; } p1;
    struct { float Obuf[4][64 * 68]; float Lbuf[4][64]; } p2;
};

__global__ __launch_bounds__(512, 2) void attn3_kernel(
    const ushort* __restrict__ Qh, const ushort* __restrict__ Ql,
    const ushort* __restrict__ Kh, const ushort* __restrict__ VhT,
    const ushort* __restrict__ VlT, const int* __restrict__ mask,
    float* __restrict__ XS)
{
    __shared__ SmemU smem;
    const int tid = threadIdx.x;
    const int wave = tid >> 6, lane = tid & 63;
    const int l15 = lane & 15, quad = lane >> 4;
    const int w4 = wave & 3, half = wave >> 2;
    const int bh = blockIdx.x, b = bh >> 3, h = bh & 7;
    const int q0 = blockIdx.y * 256;

    bf16x8 qh[4][2], ql[4][2];
    #pragma unroll
    for (int qs = 0; qs < 4; ++qs) {
        size_t qb = ((size_t)bh * 2048 + q0 + w4 * 64 + qs * 16 + l15) * 64 + quad * 8;
        qh[qs][0] = *(const bf16x8*)(Qh + qb);
        qh[qs][1] = *(const bf16x8*)(Qh + qb + 32);
        ql[qs][0] = *(const bf16x8*)(Ql + qb);
        ql[qs][1] = *(const bf16x8*)(Ql + qb + 32);
    }

    const f32x4 z = {0.f, 0.f, 0.f, 0.f};
    f32x4 oacc[4][4];
    #pragma unroll
    for (int i = 0; i < 4; ++i)
        #pragma unroll
        for (int j = 0; j < 4; ++j) oacc[i][j] = z;
    float lacc[4] = {0.f, 0.f, 0.f, 0.f};

    const int mrow0 = b * 2048 + half * 1024;
    // lane-fixed global bases: K fragment row (kv), V^T fragment row (d)
    const ushort* Kb  = Kh  + ((size_t)(bh * 2048 + half * 1024 + l15)) * 64 + quad * 8;
    const ushort* Vbh = VhT + ((size_t)(bh * 64 + l15)) * 2048 + half * 1024 + quad * 8;
    const ushort* Vbl = VlT + ((size_t)(bh * 64 + l15)) * 2048 + half * 1024 + quad * 8;
    ushort* Pw = smem.p1.Pp[wave];

    // K fragments for current t (prefetched one t ahead under PV)
    bf16x8 ka[4][2];
    #pragma unroll
    for (int kt = 0; kt < 4; ++kt) {
        ka[kt][0] = *(const bf16x8*)(Kb + (size_t)(kt * 16) * 64);
        ka[kt][1] = *(const bf16x8*)(Kb + (size_t)(kt * 16) * 64 + 32);
    }

    for (int t = 0; t < 16; ++t) {
        #pragma unroll
        for (int ks = 0; ks < 2; ++ks) {
            #pragma unroll
            for (int kt2 = 0; kt2 < 2; ++kt2) {
                const int kt = ks * 2 + kt2;
                int4 mv = *(const int4*)(mask + mrow0 + t * 64 + kt * 16 + quad * 4);
                float bias[4];
                bias[0] = mv.x ? 0.f : -1e30f; bias[1] = mv.y ? 0.f : -1e30f;
                bias[2] = mv.z ? 0.f : -1e30f; bias[3] = mv.w ? 0.f : -1e30f;
                #pragma unroll
                for (int qs = 0; qs < 4; ++qs) {
                    f32x4 a = z;
                    a = MFMA16(ka[kt][0], ql[qs][0], a);
                    a = MFMA16(ka[kt][1], ql[qs][1], a);
                    a = MFMA16(ka[kt][0], qh[qs][0], a);
                    a = MFMA16(ka[kt][1], qh[qs][1], a);
                    ushort4 hv;
                    #pragma unroll
                    for (int r = 0; r < 4; ++r) {
                        float pv = __expf(a[r] * 0.125f + bias[r]);
                        unsigned u = __float_as_uint(pv);
                        unsigned hu = (u + 0x7fffu + ((u >> 16) & 1u)) & 0xffff0000u;
                        lacc[qs] += __uint_as_float(hu);
                        ((ushort*)&hv)[r] = (ushort)(hu >> 16);
                    }
                    *(ushort4*)&Pw[(qs * 16 + l15) * LDP2 + kt2 * 16 + quad * 4] = hv;
                }
            }
            // prefetch K fragments for t+1 once all 4 kt consumed; hides L2
            // latency under the PV MFMAs below
            if (ks == 1 && t < 15) {
                #pragma unroll
                for (int kt = 0; kt < 4; ++kt) {
                    ka[kt][0] = *(const bf16x8*)(Kb + (size_t)((t + 1) * 64 + kt * 16) * 64);
                    ka[kt][1] = *(const bf16x8*)(Kb + (size_t)((t + 1) * 64 + kt * 16) * 64 + 32);
                }
            }
            // PV for this 32-kv chunk: P from per-wave LDS, V direct from global
            bf16x8 pf[4];
            #pragma unroll
            for (int qs = 0; qs < 4; ++qs)
                pf[qs] = *(const bf16x8*)&Pw[(qs * 16 + l15) * LDP2 + quad * 8];
            #pragma unroll
            for (int dsub = 0; dsub < 4; ++dsub) {
                bf16x8 vh = *(const bf16x8*)(Vbh + (size_t)(dsub * 16) * 2048 + t * 64 + ks * 32);
                bf16x8 vl = *(const bf16x8*)(Vbl + (size_t)(dsub * 16) * 2048 + t * 64 + ks * 32);
                #pragma unroll
                for (int qs = 0; qs < 4; ++qs) {
                    oacc[qs][dsub] = MFMA16(vl, pf[qs], oacc[qs][dsub]);
                    oacc[qs][dsub] = MFMA16(vh, pf[qs], oacc[qs][dsub]);
                }
            }
        }
    }

    float lv[4];
    #pragma unroll
    for (int qs = 0; qs < 4; ++qs) {
        float v = lacc[qs];
        v += __shfl_xor(v, 16);
        v += __shfl_xor(v, 32);
        lv[qs] = v;
    }

    __syncthreads();   // all waves done with Pp before Obuf aliases it
    if (half == 1) {
        #pragma unroll
        for (int qs = 0; qs < 4; ++qs) {
            #pragma unroll
            for (int dsub = 0; dsub < 4; ++dsub) {
                float4 o4 = {oacc[qs][dsub][0], oacc[qs][dsub][1], oacc[qs][dsub][2], oacc[qs][dsub][3]};
                *(float4*)&smem.p2.Obuf[w4][(qs * 16 + l15) * 68 + dsub * 16 + quad * 4] = o4;
            }
            if (quad == 0) smem.p2.Lbuf[w4][qs * 16 + l15] = lv[qs];
        }
    }
    __syncthreads();
    if (half == 0) {
        #pragma unroll
        for (int qs = 0; qs < 4; ++qs) {
            float ltot = lv[qs] + smem.p2.Lbuf[w4][qs * 16 + l15];
            float inv = (ltot > 0.f) ? 1.f / ltot : 0.f;
            int row = q0 + w4 * 64 + qs * 16 + l15;
            float* rowp = XS + ((size_t)(b * 2048 + row)) * 512 + h * 64;
            #pragma unroll
            for (int dsub = 0; dsub < 4; ++dsub) {
                float4 p4 = *(const float4*)&smem.p2.Obuf[w4][(qs * 16 + l15) * 68 + dsub * 16 + quad * 4];
                float4 o4;
                o4.x = (oacc[qs][dsub][0] + p4.x) * inv;
                o4.y = (oacc[qs][dsub][1] + p4.y) * inv;
                o4.z = (oacc[qs][dsub][2] + p4.z) * inv;
                o4.w = (oacc[qs][dsub][3] + p4.w) * inv;
                *(float4*)(rowp + dsub * 16 + quad * 4) = o4;
            }
        }
    }
}

extern "C" void kernel_launch(void* const* d_in, const int* in_sizes, int n_in,
                              void* d_out, int out_size, void* d_ws, size_t ws_size,
                              hipStream_t stream) {
    const float* query = (const float*)d_in[0];
    const float* key   = (const float*)d_in[1];
    const float* value = (const float*)d_in[2];
    const int*   mask  = (const int*)d_in[3];
    const float* Wq = (const float*)d_in[4];
    const float* bq = (const float*)d_in[5];
    const float* Wk = (const float*)d_in[6];
    const float* bk = (const float*)d_in[7];
    const float* Wv = (const float*)d_in[8];
    const float* bv = (const float*)d_in[9];
    const float* Wo = (const float*)d_in[10];
    const float* bo = (const float*)d_in[11];

    char* w = (char*)d_ws;
    const size_t MB = (size_t)1 << 20;
    ushort* Qh  = (ushort*)(w + 0 * MB);
    ushort* Ql  = (ushort*)(w + 8 * MB);
    ushort* Khp = (ushort*)(w + 16 * MB);
    ushort* VhT = (ushort*)(w + 24 * MB);
    ushort* VlT = (ushort*)(w + 32 * MB);
    float*  XS  = (float*)(w + 40 * MB);          // 16 MB fp32
    ushort* WTh = (ushort*)(w + 56 * MB);          // [1536][512]
    ushort* WTl = WTh + (size_t)1536 * 512;
    // Wo planes reuse the Qh region (dead after attn3)
    ushort* WoTh = (ushort*)(w + 0 * MB);
    ushort* WoTl = WoTh + (size_t)512 * 512;

    wsplit3_kernel<<<dim3(8, 8, 3), 256, 0, stream>>>(Wq, Wk, Wv, WTh, WTl);
    gemm2_kernel<<<dim3(64, 24), 256, 0, stream>>>(
        query, key, value, WTh, WTl, bq, bk, bv, 0, nullptr, Qh, Ql, Khp, VhT, VlT);
    attn3_kernel<<<dim3(32, 8), 512, 0, stream>>>(Qh, Ql, Khp, VhT, VlT, mask, XS);
    wsplit3_kernel<<<dim3(8, 8, 1), 256, 0, stream>>>(Wo, Wo, Wo, WoTh, WoTl);
    gemm2_kernel<<<dim3(64, 8), 256, 0, stream>>>(
        XS, XS, XS, WoTh, WoTl, bo, bo, bo, 1, (float*)d_out,
        nullptr, nullptr, nullptr, nullptr, nullptr);
}

// Round 3
// 284.719 us; speedup vs baseline: 1.1931x; 1.1931x over previous
//
#include <hip/hip_runtime.h>
#include <math.h>

#define Bq 4
#define Lq 2048
#define NH 8
#define LDP3 36   // attn Pp row stride (ushorts): 72B = 18 banks, gcd(18,32)=2 -> minimal aliasing

typedef __attribute__((ext_vector_type(8))) __bf16 bf16x8;
typedef __attribute__((ext_vector_type(4))) float f32x4;
#define MFMA16(a,b,c) __builtin_amdgcn_mfma_f32_16x16x32_bf16(a,b,c,0,0,0)

__device__ __forceinline__ void async16(const void* g, void* l) {
    __builtin_amdgcn_global_load_lds(
        (const __attribute__((address_space(1))) unsigned int*)g,
        (__attribute__((address_space(3))) unsigned int*)l, 16, 0, 0);
}

// truncation split: x = hi + lo (+ ~2^-16 rel residual)
__device__ __forceinline__ void splitbf(float x, ushort& h, ushort& l) {
    unsigned u = __float_as_uint(x);
    h = (ushort)(u >> 16);
    float hf = __uint_as_float(u & 0xffff0000u);
    l = (ushort)(__float_as_uint(x - hf) >> 16);
}
// round-to-nearest-even bf16
__device__ __forceinline__ ushort rnebf(float x) {
    unsigned u = __float_as_uint(x);
    return (ushort)((u + 0x7fffu + ((u >> 16) & 1u)) >> 16);
}

// ---- W [512k][512n] fp32 -> WT [z*512 + n][k] bf16 hi/lo planes ----
__global__ __launch_bounds__(256) void wsplit3_kernel(
    const float* __restrict__ W0, const float* __restrict__ W1, const float* __restrict__ W2,
    ushort* __restrict__ WTh, ushort* __restrict__ WTl)
{
    __shared__ float T[64][65];
    const int z = blockIdx.z;
    const float* W = (z == 0) ? W0 : (z == 1) ? W1 : W2;
    const int k0 = blockIdx.x * 64, n0 = blockIdx.y * 64;
    const int tid = threadIdx.x;
    #pragma unroll
    for (int i = 0; i < 4; ++i) {
        int u = tid + i * 256;
        int row = u >> 4, c4 = (u & 15) * 4;
        float4 v = *(const float4*)(W + (size_t)(k0 + row) * 512 + n0 + c4);
        T[row][c4 + 0] = v.x; T[row][c4 + 1] = v.y; T[row][c4 + 2] = v.z; T[row][c4 + 3] = v.w;
    }
    __syncthreads();
    #pragma unroll
    for (int i = 0; i < 2; ++i) {
        int u = tid + i * 256;
        int d = u >> 3, c8 = (u & 7) * 8;
        ushort hs[8], ls[8];
        #pragma unroll
        for (int j = 0; j < 8; ++j) splitbf(T[c8 + j][d], hs[j], ls[j]);
        uint4 wh, wl;
        wh.x = hs[0] | ((unsigned)hs[1] << 16); wh.y = hs[2] | ((unsigned)hs[3] << 16);
        wh.z = hs[4] | ((unsigned)hs[5] << 16); wh.w = hs[6] | ((unsigned)hs[7] << 16);
        wl.x = ls[0] | ((unsigned)ls[1] << 16); wl.y = ls[2] | ((unsigned)ls[3] << 16);
        wl.z = ls[4] | ((unsigned)ls[5] << 16); wl.w = ls[6] | ((unsigned)ls[7] << 16);
        size_t off = (size_t)(z * 512 + n0 + d) * 512 + k0 + c8;
        *(uint4*)(WTh + off) = wh;
        *(uint4*)(WTl + off) = wl;
    }
}

// ---- GEMM2: 128x64 tile, BK=32, 4 waves (64x32 each), dbuf async-B staging ----
// final_=0: mi = y>>3 selects 0->Q split planes, 1->K hi plane, 2->V^T split planes
// final_=1: fp32 out to Cf
union GS {
    struct {
        ushort Ah[2][128 * 40];
        ushort Al[2][128 * 40];
        ushort Bh[2][2048];
        ushort Bl[2][2048];
    } s;
    ushort E[57344 / 2];
};

__global__ __launch_bounds__(256) void gemm2_kernel(
    const float* __restrict__ A0, const float* __restrict__ A1, const float* __restrict__ A2,
    const ushort* __restrict__ BhT, const ushort* __restrict__ BlT,
    const float* __restrict__ b0, const float* __restrict__ b1, const float* __restrict__ b2,
    int final_, float* __restrict__ Cf,
    ushort* __restrict__ Qh, ushort* __restrict__ Ql, ushort* __restrict__ Khp,
    ushort* __restrict__ VhT, ushort* __restrict__ VlT)
{
    __shared__ __align__(16) GS gs;
    const int tid = threadIdx.x;
    const int wave = tid >> 6, lane = tid & 63;
    const int l15 = lane & 15, quad = lane >> 4;
    const int m0 = blockIdx.x * 128;
    const int yy = blockIdx.y;
    const int mi = yy >> 3, n0 = (yy & 7) * 64;
    const int nglob = mi * 512 + n0;
    const float* A = (mi == 0) ? A0 : (mi == 1) ? A1 : A2;
    const float* bias = (mi == 0) ? b0 : (mi == 1) ? b1 : b2;
    const int wm = (wave & 1) * 64, wn = (wave >> 1) * 32;

    // A staging (register path, needs splitbf): rows am+32i, chunk ak4
    const int am = tid >> 3, ak4 = (tid & 7) * 4;
    // B staging (async): wave stages rows wave*16..+15 of both planes, XOR-swizzled
    const int brow = lane >> 2, bsrc = (lane & 3) ^ (brow & 3);
    const ushort* bhp = BhT + (size_t)(nglob + wave * 16 + brow) * 512 + bsrc * 8;
    const ushort* blp = BlT + (size_t)(nglob + wave * 16 + brow) * 512 + bsrc * 8;
    const int bdst = wave * 512 + lane * 8;   // ushort idx; byte = uniform + lane*16

    f32x4 acc[4][2];
    #pragma unroll
    for (int i = 0; i < 4; ++i)
        #pragma unroll
        for (int j = 0; j < 2; ++j) acc[i][j] = (f32x4){0.f, 0.f, 0.f, 0.f};

    float4 av[4];
    #pragma unroll
    for (int i = 0; i < 4; ++i)
        av[i] = *(const float4*)(A + (size_t)(m0 + am + 32 * i) * 512 + ak4);
    async16(bhp, &gs.s.Bh[0][bdst]);
    async16(blp, &gs.s.Bl[0][bdst]);
    #pragma unroll
    for (int i = 0; i < 4; ++i) {
        ushort4 h4, l4;
        splitbf(av[i].x, h4.x, l4.x); splitbf(av[i].y, h4.y, l4.y);
        splitbf(av[i].z, h4.z, l4.z); splitbf(av[i].w, h4.w, l4.w);
        *(ushort4*)&gs.s.Ah[0][(am + 32 * i) * 40 + ak4] = h4;
        *(ushort4*)&gs.s.Al[0][(am + 32 * i) * 40 + ak4] = l4;
    }

    for (int t = 0; t < 16; ++t) {
        const int p = t & 1;
        __syncthreads();   // drains async B(t) + A writes(t); all reads of buf 1-p done
        if (t < 15) {
            const int kn = (t + 1) * 32;
            async16(bhp + kn, &gs.s.Bh[1 - p][bdst]);
            async16(blp + kn, &gs.s.Bl[1 - p][bdst]);
            #pragma unroll
            for (int i = 0; i < 4; ++i)
                av[i] = *(const float4*)(A + (size_t)(m0 + am + 32 * i) * 512 + kn + ak4);
        }
        bf16x8 afh[4], afl[4];
        #pragma unroll
        for (int ms = 0; ms < 4; ++ms) {
            int off = (wm + ms * 16 + l15) * 40 + quad * 8;
            afh[ms] = *(const bf16x8*)&gs.s.Ah[p][off];
            afl[ms] = *(const bf16x8*)&gs.s.Al[p][off];
        }
        #pragma unroll
        for (int ns = 0; ns < 2; ++ns) {
            int off = (wn + ns * 16 + l15) * 32 + (quad ^ (l15 & 3)) * 8;
            bf16x8 bfh = *(const bf16x8*)&gs.s.Bh[p][off];
            bf16x8 bfl = *(const bf16x8*)&gs.s.Bl[p][off];
            #pragma unroll
            for (int ms = 0; ms < 4; ++ms) {
                acc[ms][ns] = MFMA16(afh[ms], bfl, acc[ms][ns]);
                acc[ms][ns] = MFMA16(afl[ms], bfh, acc[ms][ns]);
                acc[ms][ns] = MFMA16(afh[ms], bfh, acc[ms][ns]);
            }
        }
        if (t < 15) {
            #pragma unroll
            for (int i = 0; i < 4; ++i) {
                ushort4 h4, l4;
                splitbf(av[i].x, h4.x, l4.x); splitbf(av[i].y, h4.y, l4.y);
                splitbf(av[i].z, h4.z, l4.z); splitbf(av[i].w, h4.w, l4.w);
                *(ushort4*)&gs.s.Ah[1 - p][(am + 32 * i) * 40 + ak4] = h4;
                *(ushort4*)&gs.s.Al[1 - p][(am + 32 * i) * 40 + ak4] = l4;
            }
        }
    }

    // bias
    #pragma unroll
    for (int ns = 0; ns < 2; ++ns) {
        float bv = bias[n0 + wn + ns * 16 + l15];
        #pragma unroll
        for (int ms = 0; ms < 4; ++ms)
            #pragma unroll
            for (int r = 0; r < 4; ++r) acc[ms][ns][r] += bv;
    }

    if (final_) {   // coalesced fp32 stores (16 lanes x 4B = 64B lines)
        #pragma unroll
        for (int ns = 0; ns < 2; ++ns) {
            int col = n0 + wn + ns * 16 + l15;
            #pragma unroll
            for (int ms = 0; ms < 4; ++ms)
                #pragma unroll
                for (int r = 0; r < 4; ++r)
                    Cf[(size_t)(m0 + wm + ms * 16 + quad * 4 + r) * 512 + col] = acc[ms][ns][r];
        }
        return;
    }

    const int h0 = n0 >> 6;
    const int b = m0 >> 11, rr0 = m0 & 2047;
    const int passes = (mi == 1) ? 1 : 2;
    for (int pass = 0; pass < passes; ++pass) {
        __syncthreads();
        // acc -> LDS (V: transposed [col][row], b64; Q/K: row-major [row][col], b16)
        #pragma unroll
        for (int ms = 0; ms < 4; ++ms) {
            #pragma unroll
            for (int ns = 0; ns < 2; ++ns) {
                int cl = wn + ns * 16 + l15;
                int rl = wm + ms * 16 + quad * 4;
                if (mi == 2) {
                    ushort4 w4;
                    #pragma unroll
                    for (int r = 0; r < 4; ++r) {
                        ushort h, l; splitbf(acc[ms][ns][r], h, l);
                        ((ushort*)&w4)[r] = pass ? l : h;
                    }
                    *(ushort4*)&gs.E[cl * 136 + rl] = w4;
                } else {
                    #pragma unroll
                    for (int r = 0; r < 4; ++r) {
                        float v = acc[ms][ns][r];
                        ushort out;
                        if (mi == 1) out = rnebf(v);
                        else { ushort h, l; splitbf(v, h, l); out = pass ? l : h; }
                        gs.E[(rl + r) * 72 + cl] = out;
                    }
                }
            }
        }
        __syncthreads();
        // LDS -> global, wide coalesced uint4
        if (mi == 2) {
            ushort* dst = pass ? VlT : VhT;
            #pragma unroll
            for (int i = 0; i < 4; ++i) {
                int idx = tid + i * 256;
                int d = idx >> 4, rg = idx & 15;
                uint4 u = *(const uint4*)&gs.E[d * 136 + rg * 8];
                *(uint4*)&dst[((size_t)(b * 8 + h0) * 64 + d) * 2048 + rr0 + rg * 8] = u;
            }
        } else {
            ushort* dst = (mi == 0) ? (pass ? Ql : Qh) : Khp;
            #pragma unroll
            for (int i = 0; i < 4; ++i) {
                int idx = tid + i * 256;
                int row = idx >> 3, cg = idx & 7;
                uint4 u = *(const uint4*)&gs.E[row * 72 + cg * 8];
                *(uint4*)&dst[((size_t)(b * 8 + h0) * 2048 + rr0 + row) * 64 + cg * 8] = u;
            }
        }
    }
}

// ---- Flash attention v3: occupancy restructure ----
// q-tile 128 (grid 32 bh x 16 qb = 512 blocks -> 2 blocks/CU), kv-tile 32,
// 8 waves: 4 q-strips (32 rows) x 2 kv-halves (split-K). LDS ~66 KB so two
// blocks co-reside: 16 waves/CU (was 8). Per-wave state halved vs r0
// (qh/ql[2][2], oacc[2][4]) -> no spill under __launch_bounds__(512,4).
// Pp stride 36 (72B=18 banks, gcd 2) kills the LDP=40 4-fold bank aliasing.
union SmemU {
    struct { ushort KVs[2][6][2048]; ushort Pp[8][32 * LDP3]; } p1;   // 48K + 18K
    struct { float Obuf[4][32 * 68]; float Lbuf[4][32]; } p2;         // 35K
};

__global__ __launch_bounds__(512, 4) void attn3_kernel(
    const ushort* __restrict__ Qh, const ushort* __restrict__ Ql,
    const ushort* __restrict__ Kh, const ushort* __restrict__ VhT,
    const ushort* __restrict__ VlT, const int* __restrict__ mask,
    float* __restrict__ XS)
{
    __shared__ __align__(16) SmemU smem;
    const int tid = threadIdx.x;
    const int wave = tid >> 6, lane = tid & 63;
    const int l15 = lane & 15, quad = lane >> 4;
    const int w4 = wave & 3, half = wave >> 2;
    const int bh = blockIdx.x, b = bh >> 3, h = bh & 7;
    const int q0 = blockIdx.y * 128;

    // staging: 3 async16 per thread per t (24 KB per t: K 4K + Vh 8K + Vl 8K... 
    // sub-buffers: sb = hc*3+pc; pc0: K half [32 kv][64 d]; pc1/2: V^T [64 d][32 kv])
    const ushort* sp[3]; int sstp[3]; int dofs[3];
    #pragma unroll
    for (int j = 0; j < 3; ++j) {
        int idx = j * 512 + tid;
        int sb = idx >> 8, off = idx & 255;
        int hc = sb / 3, pc = sb % 3;
        if (pc == 0) {
            int row = off >> 3, c = off & 7;   // 32 rows x 8 chunks(16B), chunk ^= row&7
            sp[j] = Kh + ((size_t)(bh * 2048 + hc * 1024 + row)) * 64 + (c ^ (row & 7)) * 8;
            sstp[j] = 32 * 64;
        } else {
            const ushort* vp = (pc == 1) ? VhT : VlT;
            int row = off >> 2, c = off & 3;   // 64 rows x 4 chunks(16B), chunk ^= (row>>1)&3
            sp[j] = vp + ((size_t)(bh * 64 + row)) * 2048 + hc * 1024 + (c ^ ((row >> 1) & 3)) * 8;
            sstp[j] = 32;
        }
        dofs[j] = sb * 2048 + off * 8;
    }
    #pragma unroll
    for (int j = 0; j < 3; ++j)
        async16(sp[j], &smem.p1.KVs[0][0][0] + dofs[j]);

    bf16x8 qh[2][2], ql[2][2];
    #pragma unroll
    for (int qs = 0; qs < 2; ++qs) {
        size_t qb = ((size_t)bh * 2048 + q0 + w4 * 32 + qs * 16 + l15) * 64 + quad * 8;
        qh[qs][0] = *(const bf16x8*)(Qh + qb);
        qh[qs][1] = *(const bf16x8*)(Qh + qb + 32);
        ql[qs][0] = *(const bf16x8*)(Ql + qb);
        ql[qs][1] = *(const bf16x8*)(Ql + qb + 32);
    }

    const f32x4 z = {0.f, 0.f, 0.f, 0.f};
    f32x4 oacc[2][4];
    #pragma unroll
    for (int i = 0; i < 2; ++i)
        #pragma unroll
        for (int j = 0; j < 4; ++j) oacc[i][j] = z;
    float lacc[2] = {0.f, 0.f};

    const int mrow0 = b * 2048 + half * 1024;
    const int sw = (quad ^ (l15 & 7)) * 8;            // K-tile read swizzle
    const int pvv = (quad ^ ((l15 >> 1) & 3)) * 8;    // V-tile read swizzle
    ushort* Pw = smem.p1.Pp[wave];

    for (int t = 0; t < 32; ++t) {
        __syncthreads();   // drains async(t) + guards buf reuse
        if (t < 31) {
            #pragma unroll
            for (int j = 0; j < 3; ++j)
                async16(sp[j] + (size_t)(t + 1) * sstp[j], &smem.p1.KVs[(t + 1) & 1][0][0] + dofs[j]);
        }
        const int p = t & 1;
        const ushort* K0 = smem.p1.KVs[p][half * 3 + 0];
        const ushort* V0 = smem.p1.KVs[p][half * 3 + 1];
        const ushort* V1 = smem.p1.KVs[p][half * 3 + 2];

        #pragma unroll
        for (int kt = 0; kt < 2; ++kt) {
            const int kb = (kt * 16 + l15) * 64;
            bf16x8 ka0 = *(const bf16x8*)&K0[kb + sw];
            bf16x8 ka1 = *(const bf16x8*)&K0[kb + (sw ^ 32)];
            int4 mv = *(const int4*)(mask + mrow0 + t * 32 + kt * 16 + quad * 4);
            float bias[4];
            bias[0] = mv.x ? 0.f : -1e30f; bias[1] = mv.y ? 0.f : -1e30f;
            bias[2] = mv.z ? 0.f : -1e30f; bias[3] = mv.w ? 0.f : -1e30f;
            #pragma unroll
            for (int qs = 0; qs < 2; ++qs) {
                f32x4 a = z;
                a = MFMA16(ka0, ql[qs][0], a);
                a = MFMA16(ka1, ql[qs][1], a);
                a = MFMA16(ka0, qh[qs][0], a);
                a = MFMA16(ka1, qh[qs][1], a);
                ushort4 hv;
                #pragma unroll
                for (int r = 0; r < 4; ++r) {
                    float pv = __expf(a[r] * 0.125f + bias[r]);
                    unsigned u = __float_as_uint(pv);
                    unsigned hu = (u + 0x7fffu + ((u >> 16) & 1u)) & 0xffff0000u;
                    lacc[qs] += __uint_as_float(hu);
                    ((ushort*)&hv)[r] = (ushort)(hu >> 16);
                }
                *(ushort4*)&Pw[(qs * 16 + l15) * LDP3 + kt * 16 + quad * 4] = hv;
            }
        }
        bf16x8 pf[2];
        #pragma unroll
        for (int qs = 0; qs < 2; ++qs)
            pf[qs] = *(const bf16x8*)&Pw[(qs * 16 + l15) * LDP3 + quad * 8];
        #pragma unroll
        for (int dsub = 0; dsub < 4; ++dsub) {
            const int vb = (dsub * 16 + l15) * 32;
            bf16x8 vh = *(const bf16x8*)&V0[vb + pvv];
            bf16x8 vl = *(const bf16x8*)&V1[vb + pvv];
            #pragma unroll
            for (int qs = 0; qs < 2; ++qs) {
                oacc[qs][dsub] = MFMA16(vl, pf[qs], oacc[qs][dsub]);
                oacc[qs][dsub] = MFMA16(vh, pf[qs], oacc[qs][dsub]);
            }
        }
    }

    float lv[2];
    #pragma unroll
    for (int qs = 0; qs < 2; ++qs) {
        float v = lacc[qs];
        v += __shfl_xor(v, 16);
        v += __shfl_xor(v, 32);
        lv[qs] = v;
    }

    __syncthreads();   // all waves done with p1 before Obuf aliases it
    if (half == 1) {
        #pragma unroll
        for (int qs = 0; qs < 2; ++qs) {
            #pragma unroll
            for (int dsub = 0; dsub < 4; ++dsub) {
                float4 o4 = {oacc[qs][dsub][0], oacc[qs][dsub][1], oacc[qs][dsub][2], oacc[qs][dsub][3]};
                *(float4*)&smem.p2.Obuf[w4][(qs * 16 + l15) * 68 + dsub * 16 + quad * 4] = o4;
            }
            if (quad == 0) smem.p2.Lbuf[w4][qs * 16 + l15] = lv[qs];
        }
    }
    __syncthreads();
    if (half == 0) {
        #pragma unroll
        for (int qs = 0; qs < 2; ++qs) {
            float ltot = lv[qs] + smem.p2.Lbuf[w4][qs * 16 + l15];
            float inv = (ltot > 0.f) ? 1.f / ltot : 0.f;
            int row = q0 + w4 * 32 + qs * 16 + l15;
            float* rowp = XS + ((size_t)(b * 2048 + row)) * 512 + h * 64;
            #pragma unroll
            for (int dsub = 0; dsub < 4; ++dsub) {
                float4 p4 = *(const float4*)&smem.p2.Obuf[w4][(qs * 16 + l15) * 68 + dsub * 16 + quad * 4];
                float4 o4;
                o4.x = (oacc[qs][dsub][0] + p4.x) * inv;
                o4.y = (oacc[qs][dsub][1] + p4.y) * inv;
                o4.z = (oacc[qs][dsub][2] + p4.z) * inv;
                o4.w = (oacc[qs][dsub][3] + p4.w) * inv;
                *(float4*)(rowp + dsub * 16 + quad * 4) = o4;
            }
        }
    }
}

extern "C" void kernel_launch(void* const* d_in, const int* in_sizes, int n_in,
                              void* d_out, int out_size, void* d_ws, size_t ws_size,
                              hipStream_t stream) {
    const float* query = (const float*)d_in[0];
    const float* key   = (const float*)d_in[1];
    const float* value = (const float*)d_in[2];
    const int*   mask  = (const int*)d_in[3];
    const float* Wq = (const float*)d_in[4];
    const float* bq = (const float*)d_in[5];
    const float* Wk = (const float*)d_in[6];
    const float* bk = (const float*)d_in[7];
    const float* Wv = (const float*)d_in[8];
    const float* bv = (const float*)d_in[9];
    const float* Wo = (const float*)d_in[10];
    const float* bo = (const float*)d_in[11];

    char* w = (char*)d_ws;
    const size_t MB = (size_t)1 << 20;
    ushort* Qh  = (ushort*)(w + 0 * MB);
    ushort* Ql  = (ushort*)(w + 8 * MB);
    ushort* Khp = (ushort*)(w + 16 * MB);
    ushort* VhT = (ushort*)(w + 24 * MB);
    ushort* VlT = (ushort*)(w + 32 * MB);
    float*  XS  = (float*)(w + 40 * MB);          // 16 MB fp32
    ushort* WTh = (ushort*)(w + 56 * MB);          // [1536][512]
    ushort* WTl = WTh + (size_t)1536 * 512;
    // Wo planes reuse the Qh region (dead after attn3)
    ushort* WoTh = (ushort*)(w + 0 * MB);
    ushort* WoTl = WoTh + (size_t)512 * 512;

    wsplit3_kernel<<<dim3(8, 8, 3), 256, 0, stream>>>(Wq, Wk, Wv, WTh, WTl);
    gemm2_kernel<<<dim3(64, 24), 256, 0, stream>>>(
        query, key, value, WTh, WTl, bq, bk, bv, 0, nullptr, Qh, Ql, Khp, VhT, VlT);
    attn3_kernel<<<dim3(32, 16), 512, 0, stream>>>(Qh, Ql, Khp, VhT, VlT, mask, XS);
    wsplit3_kernel<<<dim3(8, 8, 1), 256, 0, stream>>>(Wo, Wo, Wo, WoTh, WoTl);
    gemm2_kernel<<<dim3(64, 8), 256, 0, stream>>>(
        XS, XS, XS, WoTh, WoTl, bo, bo, bo, 1, (float*)d_out,
        nullptr, nullptr, nullptr, nullptr, nullptr);
}

// Round 5
// 280.290 us; speedup vs baseline: 1.2119x; 1.0158x over previous
//
#include <hip/hip_runtime.h>
#include <math.h>

#define Bq 4
#define Lq 2048
#define NH 8
#define LDP4 68   // attn Pp row stride (ushorts): 136B = 34 banks, gcd(34,32)=2 -> minimal aliasing

typedef __attribute__((ext_vector_type(8))) __bf16 bf16x8;
typedef __attribute__((ext_vector_type(4))) float f32x4;
#define MFMA16(a,b,c) __builtin_amdgcn_mfma_f32_16x16x32_bf16(a,b,c,0,0,0)

__device__ __forceinline__ void async16(const void* g, void* l) {
    __builtin_amdgcn_global_load_lds(
        (const __attribute__((address_space(1))) unsigned int*)g,
        (__attribute__((address_space(3))) unsigned int*)l, 16, 0, 0);
}

// truncation split: x = hi + lo (+ ~2^-16 rel residual)
__device__ __forceinline__ void splitbf(float x, ushort& h, ushort& l) {
    unsigned u = __float_as_uint(x);
    h = (ushort)(u >> 16);
    float hf = __uint_as_float(u & 0xffff0000u);
    l = (ushort)(__float_as_uint(x - hf) >> 16);
}
// round-to-nearest-even bf16
__device__ __forceinline__ ushort rnebf(float x) {
    unsigned u = __float_as_uint(x);
    return (ushort)((u + 0x7fffu + ((u >> 16) & 1u)) >> 16);
}

// ---- W [512k][512n] fp32 -> WT [z*512 + n][k] bf16 hi/lo planes ----
__global__ __launch_bounds__(256) void wsplit3_kernel(
    const float* __restrict__ W0, const float* __restrict__ W1, const float* __restrict__ W2,
    ushort* __restrict__ WTh, ushort* __restrict__ WTl)
{
    __shared__ float T[64][65];
    const int z = blockIdx.z;
    const float* W = (z == 0) ? W0 : (z == 1) ? W1 : W2;
    const int k0 = blockIdx.x * 64, n0 = blockIdx.y * 64;
    const int tid = threadIdx.x;
    #pragma unroll
    for (int i = 0; i < 4; ++i) {
        int u = tid + i * 256;
        int row = u >> 4, c4 = (u & 15) * 4;
        float4 v = *(const float4*)(W + (size_t)(k0 + row) * 512 + n0 + c4);
        T[row][c4 + 0] = v.x; T[row][c4 + 1] = v.y; T[row][c4 + 2] = v.z; T[row][c4 + 3] = v.w;
    }
    __syncthreads();
    #pragma unroll
    for (int i = 0; i < 2; ++i) {
        int u = tid + i * 256;
        int d = u >> 3, c8 = (u & 7) * 8;
        ushort hs[8], ls[8];
        #pragma unroll
        for (int j = 0; j < 8; ++j) splitbf(T[c8 + j][d], hs[j], ls[j]);
        uint4 wh, wl;
        wh.x = hs[0] | ((unsigned)hs[1] << 16); wh.y = hs[2] | ((unsigned)hs[3] << 16);
        wh.z = hs[4] | ((unsigned)hs[5] << 16); wh.w = hs[6] | ((unsigned)hs[7] << 16);
        wl.x = ls[0] | ((unsigned)ls[1] << 16); wl.y = ls[2] | ((unsigned)ls[3] << 16);
        wl.z = ls[4] | ((unsigned)ls[5] << 16); wl.w = ls[6] | ((unsigned)ls[7] << 16);
        size_t off = (size_t)(z * 512 + n0 + d) * 512 + k0 + c8;
        *(uint4*)(WTh + off) = wh;
        *(uint4*)(WTl + off) = wl;
    }
}

// ---- GEMM2: 128x64 tile, BK=32, 4 waves (64x32 each), dbuf async-B staging ----
// final_=0: mi = y>>3 selects 0->Q split planes, 1->K hi plane, 2->V^T split planes
// final_=1: fp32 out to Cf
union GS {
    struct {
        ushort Ah[2][128 * 40];
        ushort Al[2][128 * 40];
        ushort Bh[2][2048];
        ushort Bl[2][2048];
    } s;
    ushort E[57344 / 2];
};

__global__ __launch_bounds__(256) void gemm2_kernel(
    const float* __restrict__ A0, const float* __restrict__ A1, const float* __restrict__ A2,
    const ushort* __restrict__ BhT, const ushort* __restrict__ BlT,
    const float* __restrict__ b0, const float* __restrict__ b1, const float* __restrict__ b2,
    int final_, float* __restrict__ Cf,
    ushort* __restrict__ Qh, ushort* __restrict__ Ql, ushort* __restrict__ Khp,
    ushort* __restrict__ VhT, ushort* __restrict__ VlT)
{
    __shared__ __align__(16) GS gs;
    const int tid = threadIdx.x;
    const int wave = tid >> 6, lane = tid & 63;
    const int l15 = lane & 15, quad = lane >> 4;
    const int m0 = blockIdx.x * 128;
    const int yy = blockIdx.y;
    const int mi = yy >> 3, n0 = (yy & 7) * 64;
    const int nglob = mi * 512 + n0;
    const float* A = (mi == 0) ? A0 : (mi == 1) ? A1 : A2;
    const float* bias = (mi == 0) ? b0 : (mi == 1) ? b1 : b2;
    const int wm = (wave & 1) * 64, wn = (wave >> 1) * 32;

    // A staging (register path, needs splitbf): rows am+32i, chunk ak4
    const int am = tid >> 3, ak4 = (tid & 7) * 4;
    // B staging (async): wave stages rows wave*16..+15 of both planes, XOR-swizzled
    const int brow = lane >> 2, bsrc = (lane & 3) ^ (brow & 3);
    const ushort* bhp = BhT + (size_t)(nglob + wave * 16 + brow) * 512 + bsrc * 8;
    const ushort* blp = BlT + (size_t)(nglob + wave * 16 + brow) * 512 + bsrc * 8;
    const int bdst = wave * 512 + lane * 8;   // ushort idx; byte = uniform + lane*16

    f32x4 acc[4][2];
    #pragma unroll
    for (int i = 0; i < 4; ++i)
        #pragma unroll
        for (int j = 0; j < 2; ++j) acc[i][j] = (f32x4){0.f, 0.f, 0.f, 0.f};

    float4 av[4];
    #pragma unroll
    for (int i = 0; i < 4; ++i)
        av[i] = *(const float4*)(A + (size_t)(m0 + am + 32 * i) * 512 + ak4);
    async16(bhp, &gs.s.Bh[0][bdst]);
    async16(blp, &gs.s.Bl[0][bdst]);
    #pragma unroll
    for (int i = 0; i < 4; ++i) {
        ushort4 h4, l4;
        splitbf(av[i].x, h4.x, l4.x); splitbf(av[i].y, h4.y, l4.y);
        splitbf(av[i].z, h4.z, l4.z); splitbf(av[i].w, h4.w, l4.w);
        *(ushort4*)&gs.s.Ah[0][(am + 32 * i) * 40 + ak4] = h4;
        *(ushort4*)&gs.s.Al[0][(am + 32 * i) * 40 + ak4] = l4;
    }

    for (int t = 0; t < 16; ++t) {
        const int p = t & 1;
        __syncthreads();   // drains async B(t) + A writes(t); all reads of buf 1-p done
        if (t < 15) {
            const int kn = (t + 1) * 32;
            async16(bhp + kn, &gs.s.Bh[1 - p][bdst]);
            async16(blp + kn, &gs.s.Bl[1 - p][bdst]);
            #pragma unroll
            for (int i = 0; i < 4; ++i)
                av[i] = *(const float4*)(A + (size_t)(m0 + am + 32 * i) * 512 + kn + ak4);
        }
        bf16x8 afh[4], afl[4];
        #pragma unroll
        for (int ms = 0; ms < 4; ++ms) {
            int off = (wm + ms * 16 + l15) * 40 + quad * 8;
            afh[ms] = *(const bf16x8*)&gs.s.Ah[p][off];
            afl[ms] = *(const bf16x8*)&gs.s.Al[p][off];
        }
        #pragma unroll
        for (int ns = 0; ns < 2; ++ns) {
            int off = (wn + ns * 16 + l15) * 32 + (quad ^ (l15 & 3)) * 8;
            bf16x8 bfh = *(const bf16x8*)&gs.s.Bh[p][off];
            bf16x8 bfl = *(const bf16x8*)&gs.s.Bl[p][off];
            #pragma unroll
            for (int ms = 0; ms < 4; ++ms) {
                acc[ms][ns] = MFMA16(afh[ms], bfl, acc[ms][ns]);
                acc[ms][ns] = MFMA16(afl[ms], bfh, acc[ms][ns]);
                acc[ms][ns] = MFMA16(afh[ms], bfh, acc[ms][ns]);
            }
        }
        if (t < 15) {
            #pragma unroll
            for (int i = 0; i < 4; ++i) {
                ushort4 h4, l4;
                splitbf(av[i].x, h4.x, l4.x); splitbf(av[i].y, h4.y, l4.y);
                splitbf(av[i].z, h4.z, l4.z); splitbf(av[i].w, h4.w, l4.w);
                *(ushort4*)&gs.s.Ah[1 - p][(am + 32 * i) * 40 + ak4] = h4;
                *(ushort4*)&gs.s.Al[1 - p][(am + 32 * i) * 40 + ak4] = l4;
            }
        }
    }

    // bias
    #pragma unroll
    for (int ns = 0; ns < 2; ++ns) {
        float bv = bias[n0 + wn + ns * 16 + l15];
        #pragma unroll
        for (int ms = 0; ms < 4; ++ms)
            #pragma unroll
            for (int r = 0; r < 4; ++r) acc[ms][ns][r] += bv;
    }

    if (final_) {   // coalesced fp32 stores (16 lanes x 4B = 64B lines)
        #pragma unroll
        for (int ns = 0; ns < 2; ++ns) {
            int col = n0 + wn + ns * 16 + l15;
            #pragma unroll
            for (int ms = 0; ms < 4; ++ms)
                #pragma unroll
                for (int r = 0; r < 4; ++r)
                    Cf[(size_t)(m0 + wm + ms * 16 + quad * 4 + r) * 512 + col] = acc[ms][ns][r];
        }
        return;
    }

    const int h0 = n0 >> 6;
    const int b = m0 >> 11, rr0 = m0 & 2047;
    const int passes = (mi == 1) ? 1 : 2;
    for (int pass = 0; pass < passes; ++pass) {
        __syncthreads();
        // acc -> LDS (V: transposed [col][row], b64; Q/K: row-major [row][col], b16)
        #pragma unroll
        for (int ms = 0; ms < 4; ++ms) {
            #pragma unroll
            for (int ns = 0; ns < 2; ++ns) {
                int cl = wn + ns * 16 + l15;
                int rl = wm + ms * 16 + quad * 4;
                if (mi == 2) {
                    ushort4 w4;
                    #pragma unroll
                    for (int r = 0; r < 4; ++r) {
                        ushort h, l; splitbf(acc[ms][ns][r], h, l);
                        ((ushort*)&w4)[r] = pass ? l : h;
                    }
                    *(ushort4*)&gs.E[cl * 136 + rl] = w4;
                } else {
                    #pragma unroll
                    for (int r = 0; r < 4; ++r) {
                        float v = acc[ms][ns][r];
                        ushort out;
                        if (mi == 1) out = rnebf(v);
                        else { ushort h, l; splitbf(v, h, l); out = pass ? l : h; }
                        gs.E[(rl + r) * 72 + cl] = out;
                    }
                }
            }
        }
        __syncthreads();
        // LDS -> global, wide coalesced uint4
        if (mi == 2) {
            ushort* dst = pass ? VlT : VhT;
            #pragma unroll
            for (int i = 0; i < 4; ++i) {
                int idx = tid + i * 256;
                int d = idx >> 4, rg = idx & 15;
                uint4 u = *(const uint4*)&gs.E[d * 136 + rg * 8];
                *(uint4*)&dst[((size_t)(b * 8 + h0) * 64 + d) * 2048 + rr0 + rg * 8] = u;
            }
        } else {
            ushort* dst = (mi == 0) ? (pass ? Ql : Qh) : Khp;
            #pragma unroll
            for (int i = 0; i < 4; ++i) {
                int idx = tid + i * 256;
                int row = idx >> 3, cg = idx & 7;
                uint4 u = *(const uint4*)&gs.E[row * 72 + cg * 8];
                *(uint4*)&dst[((size_t)(b * 8 + h0) * 2048 + rr0 + row) * 64 + cg * 8] = u;
            }
        }
    }
}

// ---- Flash attention v4b: no split-K, full 2048 kv (32 t-tiles), 2 blocks/CU ----
// 8 waves x 16 q-rows = q-tile 128 (grid 32 x 16 = 512 blocks, 2 blocks/CU).
// All waves share one kv-64 tile per t, t = 0..31 covers all 2048 kv (v4 bug:
// only went to 16 = half the keys). Per-t stage = K 8K + Vh 8K + Vl 8K; dbuf
// 48K + Pp 17K = 65 KB -> 2 co-resident blocks (16 waves/CU). 32 MFMA per
// wave per barrier (r0 ratio) and NO split-K epilogue: lacc reduces via shfl,
// O writes straight to XS. VGPR tiny (qh/ql[2], oacc[4]).
struct SmemA {
    ushort KVs[2][3][4096];   // [buf][K,Vh,Vl][64x64 bf16], 49152 B
    ushort Pp[8][16 * LDP4];  // per-wave P rows, 17408 B
};

__global__ __launch_bounds__(512, 4) void attn3_kernel(
    const ushort* __restrict__ Qh, const ushort* __restrict__ Ql,
    const ushort* __restrict__ Kh, const ushort* __restrict__ VhT,
    const ushort* __restrict__ VlT, const int* __restrict__ mask,
    float* __restrict__ XS)
{
    __shared__ __align__(16) SmemA smem;
    const int tid = threadIdx.x;
    const int wave = tid >> 6, lane = tid & 63;
    const int l15 = lane & 15, quad = lane >> 4;
    const int bh = blockIdx.x, b = bh >> 3, h = bh & 7;
    const int q0 = blockIdx.y * 128;

    // staging: 3 async16 per thread per t (24 KB/t). Sub-buffers of 512 slots:
    // j=0: K [64 kv][8 chunks], j=1/2: V^T planes [64 d][8 chunks], chunk ^= row&7
    const int srow = tid >> 3, sc = ((tid & 7) ^ (srow & 7)) * 8;
    const ushort* sp[3]; int sstp[3];
    sp[0] = Kh  + ((size_t)(bh * 2048 + srow)) * 64 + sc;   sstp[0] = 64 * 64;
    sp[1] = VhT + ((size_t)(bh * 64 + srow)) * 2048 + sc;   sstp[1] = 64;
    sp[2] = VlT + ((size_t)(bh * 64 + srow)) * 2048 + sc;   sstp[2] = 64;
    const int dofs = tid * 8;   // within each 4096-ushort sub-buffer

    #pragma unroll
    for (int j = 0; j < 3; ++j)
        async16(sp[j], &smem.KVs[0][j][dofs]);

    bf16x8 qhf[2], qlf[2];
    {
        size_t qb = ((size_t)bh * 2048 + q0 + wave * 16 + l15) * 64 + quad * 8;
        qhf[0] = *(const bf16x8*)(Qh + qb);
        qhf[1] = *(const bf16x8*)(Qh + qb + 32);
        qlf[0] = *(const bf16x8*)(Ql + qb);
        qlf[1] = *(const bf16x8*)(Ql + qb + 32);
    }

    const f32x4 z = {0.f, 0.f, 0.f, 0.f};
    f32x4 oacc[4];
    #pragma unroll
    for (int j = 0; j < 4; ++j) oacc[j] = z;
    float lacc = 0.f;

    const int mrow0 = b * 2048;
    const int sw = (quad ^ (l15 & 7)) * 8;   // K/V tile read swizzle
    ushort* Pw = smem.Pp[wave];

    for (int t = 0; t < 32; ++t) {   // 32 x 64 kv = full 2048
        __syncthreads();   // drains async(t) + guards buf reuse
        if (t < 31) {
            #pragma unroll
            for (int j = 0; j < 3; ++j)
                async16(sp[j] + (size_t)(t + 1) * sstp[j], &smem.KVs[(t + 1) & 1][j][dofs]);
        }
        const int p = t & 1;
        const ushort* K0 = smem.KVs[p][0];
        const ushort* V0 = smem.KVs[p][1];
        const ushort* V1 = smem.KVs[p][2];

        #pragma unroll
        for (int kt = 0; kt < 4; ++kt) {
            const int kb = (kt * 16 + l15) * 64;
            bf16x8 ka0 = *(const bf16x8*)&K0[kb + sw];
            bf16x8 ka1 = *(const bf16x8*)&K0[kb + (sw ^ 32)];
            int4 mv = *(const int4*)(mask + mrow0 + t * 64 + kt * 16 + quad * 4);
            float bias[4];
            bias[0] = mv.x ? 0.f : -1e30f; bias[1] = mv.y ? 0.f : -1e30f;
            bias[2] = mv.z ? 0.f : -1e30f; bias[3] = mv.w ? 0.f : -1e30f;
            f32x4 a = z;
            a = MFMA16(ka0, qlf[0], a);
            a = MFMA16(ka1, qlf[1], a);
            a = MFMA16(ka0, qhf[0], a);
            a = MFMA16(ka1, qhf[1], a);
            ushort4 hv;
            #pragma unroll
            for (int r = 0; r < 4; ++r) {
                float pv = __expf(a[r] * 0.125f + bias[r]);
                unsigned u = __float_as_uint(pv);
                unsigned hu = (u + 0x7fffu + ((u >> 16) & 1u)) & 0xffff0000u;
                lacc += __uint_as_float(hu);
                ((ushort*)&hv)[r] = (ushort)(hu >> 16);
            }
            *(ushort4*)&Pw[l15 * LDP4 + kt * 16 + quad * 4] = hv;
        }
        #pragma unroll
        for (int ks = 0; ks < 2; ++ks) {
            bf16x8 pf = *(const bf16x8*)&Pw[l15 * LDP4 + ks * 32 + quad * 8];
            const int svo = sw ^ (ks * 32);
            #pragma unroll
            for (int dsub = 0; dsub < 4; ++dsub) {
                const int vb = (dsub * 16 + l15) * 64;
                bf16x8 vh = *(const bf16x8*)&V0[vb + svo];
                bf16x8 vl = *(const bf16x8*)&V1[vb + svo];
                oacc[dsub] = MFMA16(vl, pf, oacc[dsub]);
                oacc[dsub] = MFMA16(vh, pf, oacc[dsub]);
            }
        }
    }

    // row-sum across the 4 quads holding this q row's kv partials
    float lv = lacc;
    lv += __shfl_xor(lv, 16);
    lv += __shfl_xor(lv, 32);
    float inv = (lv > 0.f) ? 1.f / lv : 0.f;

    const int row = q0 + wave * 16 + l15;
    float* rowp = XS + ((size_t)(b * 2048 + row)) * 512 + h * 64;
    #pragma unroll
    for (int dsub = 0; dsub < 4; ++dsub) {
        float4 o4;
        o4.x = oacc[dsub][0] * inv;
        o4.y = oacc[dsub][1] * inv;
        o4.z = oacc[dsub][2] * inv;
        o4.w = oacc[dsub][3] * inv;
        *(float4*)(rowp + dsub * 16 + quad * 4) = o4;
    }
}

extern "C" void kernel_launch(void* const* d_in, const int* in_sizes, int n_in,
                              void* d_out, int out_size, void* d_ws, size_t ws_size,
                              hipStream_t stream) {
    const float* query = (const float*)d_in[0];
    const float* key   = (const float*)d_in[1];
    const float* value = (const float*)d_in[2];
    const int*   mask  = (const int*)d_in[3];
    const float* Wq = (const float*)d_in[4];
    const float* bq = (const float*)d_in[5];
    const float* Wk = (const float*)d_in[6];
    const float* bk = (const float*)d_in[7];
    const float* Wv = (const float*)d_in[8];
    const float* bv = (const float*)d_in[9];
    const float* Wo = (const float*)d_in[10];
    const float* bo = (const float*)d_in[11];

    char* w = (char*)d_ws;
    const size_t MB = (size_t)1 << 20;
    ushort* Qh  = (ushort*)(w + 0 * MB);
    ushort* Ql  = (ushort*)(w + 8 * MB);
    ushort* Khp = (ushort*)(w + 16 * MB);
    ushort* VhT = (ushort*)(w + 24 * MB);
    ushort* VlT = (ushort*)(w + 32 * MB);
    float*  XS  = (float*)(w + 40 * MB);          // 16 MB fp32
    ushort* WTh = (ushort*)(w + 56 * MB);          // [1536][512]
    ushort* WTl = WTh + (size_t)1536 * 512;
    // Wo planes reuse the Qh region (dead after attn3)
    ushort* WoTh = (ushort*)(w + 0 * MB);
    ushort* WoTl = WoTh + (size_t)512 * 512;

    wsplit3_kernel<<<dim3(8, 8, 3), 256, 0, stream>>>(Wq, Wk, Wv, WTh, WTl);
    gemm2_kernel<<<dim3(64, 24), 256, 0, stream>>>(
        query, key, value, WTh, WTl, bq, bk, bv, 0, nullptr, Qh, Ql, Khp, VhT, VlT);
    attn3_kernel<<<dim3(32, 16), 512, 0, stream>>>(Qh, Ql, Khp, VhT, VlT, mask, XS);
    wsplit3_kernel<<<dim3(8, 8, 1), 256, 0, stream>>>(Wo, Wo, Wo, WoTh, WoTl);
    gemm2_kernel<<<dim3(64, 8), 256, 0, stream>>>(
        XS, XS, XS, WoTh, WoTl, bo, bo, bo, 1, (float*)d_out,
        nullptr, nullptr, nullptr, nullptr, nullptr);
}